// Round 3
// baseline (343.466 us; speedup 1.0000x reference)
//
#include <hip/hip_runtime.h>
#include <cstdint>
#include <cstddef>

typedef unsigned short u16;
typedef __bf16 bf16x8 __attribute__((ext_vector_type(8)));
typedef float f32x4 __attribute__((ext_vector_type(4)));
typedef unsigned short u16x8 __attribute__((ext_vector_type(8)));

#define SEQ 4096
#define HID 2048
#define NH 16
#define HD 128
#define WIN 1024

__device__ __forceinline__ float bf2f(u16 u) {
  union { unsigned int i; float f; } v; v.i = ((unsigned int)u) << 16; return v.f;
}
__device__ __forceinline__ u16 f2bf(float f) {
  union { float f; unsigned int i; } v; v.f = f;
  unsigned int r = v.i + 0x7FFFu + ((v.i >> 16) & 1u);
  return (u16)(r >> 16);
}
__device__ __forceinline__ u16 f2bf_rne(float f) {
  union { __bf16 b; u16 u; } v; v.b = (__bf16)f; return v.u;
}
__device__ __forceinline__ float exp2a(float x) {
  float r; asm("v_exp_f32 %0, %1" : "=v"(r) : "v"(x)); return r;
}
// XOR swizzle within a tile whose rows are (1<<L2R) bytes. Involution; keeps 16B alignment.
template<int L2R>
__device__ __forceinline__ unsigned swz(unsigned o) { return o ^ (((o >> L2R) & 7u) << 4); }

__device__ __forceinline__ void gload_lds16(const u16* g, u16* l) {
  __builtin_amdgcn_global_load_lds((const __attribute__((address_space(1))) void*)g,
                                   (__attribute__((address_space(3))) void*)l, 16, 0, 0);
}

// ---------------- elementwise prep ----------------

__global__ void cast_f32_bf16(const float* __restrict__ in, u16* __restrict__ out, int n4) {
  int i = blockIdx.x * blockDim.x + threadIdx.x;
  if (i < n4) {
    float4 v = ((const float4*)in)[i];
    union { u16 u[4]; unsigned long long ll; } r;
    r.u[0] = f2bf(v.x); r.u[1] = f2bf(v.y); r.u[2] = f2bf(v.z); r.u[3] = f2bf(v.w);
    ((unsigned long long*)out)[i] = r.ll;
  }
}

// W (HID x HID, f32, row-major) -> Wt (HID x HID, bf16, transposed)
__global__ void transpose_cast(const float* __restrict__ W, u16* __restrict__ Wt) {
  __shared__ float t[32][33];
  const int tx = threadIdx.x & 31, ty = threadIdx.x >> 5;  // ty 0..7
  const int x0 = blockIdx.x * 32, y0 = blockIdx.y * 32;
#pragma unroll
  for (int i = 0; i < 4; ++i)
    t[ty + i * 8][tx] = W[(size_t)(y0 + ty + i * 8) * HID + x0 + tx];
  __syncthreads();
#pragma unroll
  for (int i = 0; i < 4; ++i)
    Wt[(size_t)(x0 + ty + i * 8) * HID + y0 + tx] = f2bf(t[tx][ty + i * 8]);
}

__global__ void rope_table(float* __restrict__ ctab, float* __restrict__ stab) {
  int idx = blockIdx.x * blockDim.x + threadIdx.x;  // SEQ*64
  int pos = idx >> 6, i = idx & 63;
  float invf = expf(-(float)i * 0.14391156831212787f);  // ln(10000)/64
  float ang = (float)pos * invf;
  float s, c;
  sincosf(ang, &s, &c);
  ctab[idx] = c; stab[idx] = s;
}

// in-place RoPE on Q and K (bf16 [SEQ][HID])
__global__ void rope_apply(u16* __restrict__ Qb, u16* __restrict__ Kb,
                           const float* __restrict__ ctab, const float* __restrict__ stab) {
  int idx = blockIdx.x * blockDim.x + threadIdx.x;  // SEQ*NH*64
  int pos = idx >> 10;
  int rem = idx & 1023;
  int h = rem >> 6, i = rem & 63;
  size_t base = (size_t)pos * HID + h * HD + i;
  float c = ctab[(pos << 6) + i], s = stab[(pos << 6) + i];
  float q1 = bf2f(Qb[base]), q2 = bf2f(Qb[base + 64]);
  Qb[base] = f2bf(q1 * c - q2 * s);
  Qb[base + 64] = f2bf(q2 * c + q1 * s);
  float k1 = bf2f(Kb[base]), k2 = bf2f(Kb[base + 64]);
  Kb[base] = f2bf(k1 * c - k2 * s);
  Kb[base + 64] = f2bf(k2 * c + k1 * s);
}

// ---------------- GEMM: C[M,N] = A[M,K] * Bt[N,K]^T, bf16 in, fp32 acc ----------------

template<bool OUT_F32>
__device__ __forceinline__ void gemm_body(const u16* __restrict__ A, const u16* __restrict__ Bt,
                                          void* __restrict__ C, int brow, int bcol,
                                          u16 (&ldsA)[2][8192], u16 (&ldsB)[2][8192]) {
  const int lane = threadIdx.x & 63;
  const int wv = threadIdx.x >> 6;
  const int wr = wv >> 1, wc = wv & 1;
  const int K = HID, N = HID;

  const f32x4 zero = {0.f, 0.f, 0.f, 0.f};
  f32x4 acc[4][4];
#pragma unroll
  for (int m = 0; m < 4; ++m)
#pragma unroll
    for (int n = 0; n < 4; ++n) acc[m][n] = zero;

  auto stage = [&](int buf, int kt) {
    const int k0 = kt * 64;
#pragma unroll
    for (int i = 0; i < 4; ++i) {
      unsigned o = ((unsigned)(wv * 4 + i) * 64 + (unsigned)lane) * 16u;
      unsigned r = o >> 7;                 // tile row (128B rows: 64 bf16)
      unsigned cb = swz<7>(o) & 127u;      // swizzled col-bytes within row
      const size_t gcol = (size_t)k0 + (cb >> 1);
      gload_lds16(A + (size_t)(brow + r) * K + gcol, &ldsA[buf][(wv * 4 + i) * 512]);
      gload_lds16(Bt + (size_t)(bcol + r) * K + gcol, &ldsB[buf][(wv * 4 + i) * 512]);
    }
  };

  stage(0, 0);
  __syncthreads();
  int buf = 0;
  const int nt = K / 64;
  for (int kt = 0; kt < nt; ++kt) {
    if (kt + 1 < nt) stage(buf ^ 1, kt + 1);
    __builtin_amdgcn_s_setprio(1);
#pragma unroll
    for (int s = 0; s < 2; ++s) {
      const unsigned kb = (unsigned)(s * 64 + ((lane >> 4) & 3) * 16);
      bf16x8 af[4], bfv[4];
#pragma unroll
      for (int m = 0; m < 4; ++m) {
        unsigned row = wr * 64 + m * 16 + (lane & 15);
        af[m] = *(const bf16x8*)((const char*)&ldsA[buf][0] + swz<7>(row * 128 + kb));
      }
#pragma unroll
      for (int n = 0; n < 4; ++n) {
        unsigned row = wc * 64 + n * 16 + (lane & 15);
        bfv[n] = *(const bf16x8*)((const char*)&ldsB[buf][0] + swz<7>(row * 128 + kb));
      }
#pragma unroll
      for (int m = 0; m < 4; ++m)
#pragma unroll
        for (int n = 0; n < 4; ++n)
          acc[m][n] = __builtin_amdgcn_mfma_f32_16x16x32_bf16(af[m], bfv[n], acc[m][n], 0, 0, 0);
    }
    __builtin_amdgcn_s_setprio(0);
    __syncthreads();
    buf ^= 1;
  }

#pragma unroll
  for (int m = 0; m < 4; ++m) {
    const int rbase = brow + wr * 64 + m * 16 + ((lane >> 4) & 3) * 4;
#pragma unroll
    for (int n = 0; n < 4; ++n) {
      const int cbase = bcol + wc * 64 + n * 16 + (lane & 15);
#pragma unroll
      for (int r = 0; r < 4; ++r) {
        const size_t idx = (size_t)(rbase + r) * N + cbase;
        if (OUT_F32) ((float*)C)[idx] = acc[m][n][r];
        else ((u16*)C)[idx] = f2bf(acc[m][n][r]);
      }
    }
  }
}

__global__ __launch_bounds__(256, 2) void gemm_qkv_kernel(
    const u16* __restrict__ X, const u16* __restrict__ Wqt, const u16* __restrict__ Wkt,
    const u16* __restrict__ Wvt, u16* __restrict__ Qo, u16* __restrict__ Ko, u16* __restrict__ Vo) {
  __shared__ u16 ldsA[2][8192];
  __shared__ u16 ldsB[2][8192];
  // T1 bijective XCD swizzle: 1536 blocks = 8 * 192
  int flat = (blockIdx.z * 32 + blockIdx.y) * 16 + blockIdx.x;
  int nf = (flat & 7) * 192 + (flat >> 3);
  int bx = nf & 15, by = (nf >> 4) & 31, bz = nf >> 9;
  const u16* Bt = (bz == 0) ? Wqt : (bz == 1) ? Wkt : Wvt;
  u16* C = (bz == 0) ? Qo : (bz == 1) ? Ko : Vo;
  gemm_body<false>(X, Bt, C, by * 128, bx * 128, ldsA, ldsB);
}

__global__ __launch_bounds__(256, 2) void gemm_out_kernel(
    const u16* __restrict__ Ob, const u16* __restrict__ Wot, float* __restrict__ out) {
  __shared__ u16 ldsA[2][8192];
  __shared__ u16 ldsB[2][8192];
  // 512 blocks = 8 * 64
  int flat = blockIdx.y * 16 + blockIdx.x;
  int nf = (flat & 7) * 64 + (flat >> 3);
  int bx = nf & 15, by = nf >> 4;
  gemm_body<true>(Ob, Wot, out, by * 128, bx * 128, ldsA, ldsB);
}

// ---------------- windowed flash attention ----------------
// block = (head, 128 q-rows); 8 waves x 16 rows; KV tiles of 64; 512 threads.
// LDS exactly 80KB -> 2 blocks/CU (160KB pool). All tiles XOR-swizzled, no pads.
// One barrier per tile; per-wave tile skip; exact per-wave causal/window masks.

__global__ __launch_bounds__(512, 4) void attn_kernel(
    const u16* __restrict__ Q, const u16* __restrict__ K,
    const u16* __restrict__ V, u16* __restrict__ O) {
  __shared__ u16 k_lds[2][8192];   // [64 keys][128 d] swizzled (256B rows), dbuf  32KB
  __shared__ u16 vt_lds[2][8192];  // V^T [128 d][64 keys] swizzled (128B rows), dbuf 32KB
  __shared__ u16 p_lds[8][1024];   // per-wave P [16 q][64 k] swizzled (128B rows)   16KB

  const int lane = threadIdx.x & 63;
  const int wv = threadIdx.x >> 6;   // 0..7
  const int g = lane >> 4;           // 0..3
  const int c = lane & 15;

  // T1 chunked swizzle: 512 blocks = 8 XCDs x 64; each XCD gets 2 whole heads
  int flat = blockIdx.y * 32 + blockIdx.x;
  int nf = (flat & 7) * 64 + (flat >> 3);
  const int q0 = (nf & 31) * 128;
  const int h = nf >> 5;
  const int qw = q0 + wv * 16;       // this wave's first q row

  // Q fragments straight from global (row read once; L2-resident)
  bf16x8 qf[4];
  {
    const u16* qrow = Q + (size_t)(qw + c) * HID + h * HD;
#pragma unroll
    for (int s = 0; s < 4; ++s)
      qf[s] = *(const bf16x8*)(qrow + s * 32 + g * 8);
  }

  const int t_start = (q0 >= WIN) ? (q0 - WIN) : 0;
  const int t_end = q0 + 64;  // last tile (covers rows q0+64..q0+127 diagonal)

  auto stageK = [&](int buf, int t0) {
#pragma unroll
    for (int i = 0; i < 2; ++i) {
      unsigned idx = (unsigned)(i * 512 + threadIdx.x);  // 0..1023 16B-chunks
      unsigned o = idx * 16u;
      unsigned r = o >> 8;
      unsigned cb = swz<8>(o) & 255u;
      gload_lds16(K + (size_t)(t0 + r) * HID + h * HD + (cb >> 1), &k_lds[buf][idx * 8]);
    }
  };
  auto loadV = [&](int t0, u16x8* vr) {
    const u16x8* src = (const u16x8*)(V + (size_t)(t0 + lane) * HID + h * HD + wv * 16);
    vr[0] = src[0];
    vr[1] = src[1];
  };
  auto writeVT = [&](int buf, const u16x8* vr) {
#pragma unroll
    for (int it = 0; it < 2; ++it)
#pragma unroll
      for (int j = 0; j < 8; ++j) {
        const int d = wv * 16 + it * 8 + j;
        vt_lds[buf][d * 64 + (lane ^ ((d & 7) << 3))] = vr[it][j];
      }
  };

  // prologue: stage tile t_start into buffer 0
  {
    u16x8 vr[2];
    stageK(0, t_start);
    loadV(t_start, vr);
    writeVT(0, vr);
  }
  __syncthreads();

  const f32x4 zero = {0.f, 0.f, 0.f, 0.f};
  float mrow[4], lrow[4];
  f32x4 oacc[8];
#pragma unroll
  for (int r = 0; r < 4; ++r) { mrow[r] = -1e30f; lrow[r] = 0.f; }
#pragma unroll
  for (int d = 0; d < 8; ++d) oacc[d] = zero;

  const float scale2 = 0.12751743f;  // (1/sqrt(128)) * log2(e)
  int b = 0;

  for (int t0 = t_start; t0 <= t_end; t0 += 64) {
    const int nb = b ^ 1;
    const bool has_next = (t0 + 64 <= t_end);

    // issue next tile's staging early (T14 async split)
    u16x8 vr[2];
    if (has_next) {
      stageK(nb, t0 + 64);
      loadV(t0 + 64, vr);
    }

    // this wave computes this tile?
    const bool compute = (t0 <= qw + 15) && (t0 + 63 >= qw - (WIN - 1));

    if (compute) {
      // S = Q K^T  (16 q x 64 keys)
      f32x4 sa[4];
#pragma unroll
      for (int kf = 0; kf < 4; ++kf) sa[kf] = zero;
      __builtin_amdgcn_s_setprio(1);
#pragma unroll
      for (int s = 0; s < 4; ++s) {
#pragma unroll
        for (int kf = 0; kf < 4; ++kf) {
          const int row = kf * 16 + c;
          const bf16x8 kb = *(const bf16x8*)&k_lds[b][row * 128 + ((s * 32 + g * 8) ^ ((row & 7) << 3))];
          sa[kf] = __builtin_amdgcn_mfma_f32_16x16x32_bf16(qf[s], kb, sa[kf], 0, 0, 0);
        }
      }
      __builtin_amdgcn_s_setprio(0);

      // scale (exp2 domain) + mask only where needed (per-wave exact)
      const int qbase = qw + g * 4;
      const bool causal = (t0 + 63 > qw);
      const bool edge = (t0 < qw - (WIN - 16));  // t0 < qw+15-(WIN-1)
      if (causal) {
#pragma unroll
        for (int kf = 0; kf < 4; ++kf) {
          const int kpos = t0 + kf * 16 + c;
#pragma unroll
          for (int r = 0; r < 4; ++r) {
            float x = sa[kf][r] * scale2;
            sa[kf][r] = (kpos <= qbase + r) ? x : -1e30f;
          }
        }
      } else if (edge) {
#pragma unroll
        for (int kf = 0; kf < 4; ++kf) {
          const int kpos = t0 + kf * 16 + c;
#pragma unroll
          for (int r = 0; r < 4; ++r) {
            float x = sa[kf][r] * scale2;
            sa[kf][r] = (kpos > qbase + r - WIN) ? x : -1e30f;
          }
        }
      } else {
#pragma unroll
        for (int kf = 0; kf < 4; ++kf)
#pragma unroll
          for (int r = 0; r < 4; ++r) sa[kf][r] *= scale2;
      }

      // row max
      float tmax[4];
#pragma unroll
      for (int r = 0; r < 4; ++r)
        tmax[r] = fmaxf(fmaxf(sa[0][r], sa[1][r]), fmaxf(sa[2][r], sa[3][r]));
#pragma unroll
      for (int r = 0; r < 4; ++r)
#pragma unroll
        for (int d = 1; d < 16; d <<= 1)
          tmax[r] = fmaxf(tmax[r], __shfl_xor(tmax[r], d, 16));

      // T13 defer-rescale
      bool okl = (tmax[0] <= mrow[0] + 8.f) && (tmax[1] <= mrow[1] + 8.f) &&
                 (tmax[2] <= mrow[2] + 8.f) && (tmax[3] <= mrow[3] + 8.f);
      if (!__all((int)okl)) {
#pragma unroll
        for (int r = 0; r < 4; ++r) {
          const float mn = fmaxf(mrow[r], tmax[r]);
          const float al = exp2a(mrow[r] - mn);
          mrow[r] = mn;
          lrow[r] *= al;
#pragma unroll
          for (int df = 0; df < 8; ++df) oacc[df][r] *= al;
        }
      }

      // P = exp2(S - m); row-sum
      float rs[4] = {0.f, 0.f, 0.f, 0.f};
      if (causal || edge) {
#pragma unroll
        for (int kf = 0; kf < 4; ++kf)
#pragma unroll
          for (int r = 0; r < 4; ++r) {
            const float x = sa[kf][r];
            const float p = (x < -1e29f) ? 0.f : exp2a(x - mrow[r]);
            sa[kf][r] = p; rs[r] += p;
          }
      } else {
#pragma unroll
        for (int kf = 0; kf < 4; ++kf)
#pragma unroll
          for (int r = 0; r < 4; ++r) {
            const float p = exp2a(sa[kf][r] - mrow[r]);
            sa[kf][r] = p; rs[r] += p;
          }
      }
#pragma unroll
      for (int r = 0; r < 4; ++r) {
#pragma unroll
        for (int d = 1; d < 16; d <<= 1) rs[r] += __shfl_xor(rs[r], d, 16);
        lrow[r] += rs[r];
      }

      // P -> per-wave LDS (swizzled [16][64])
#pragma unroll
      for (int kf = 0; kf < 4; ++kf)
#pragma unroll
        for (int r = 0; r < 4; ++r) {
          const int q = g * 4 + r;
          p_lds[wv][q * 64 + ((kf * 16 + c) ^ ((q & 7) << 3))] = f2bf_rne(sa[kf][r]);
        }
    }

    // write next tile's V^T (loads have had QK^T + softmax to land)
    if (has_next) writeVT(nb, vr);

    asm volatile("" ::: "memory");  // order p_lds writes before PV reads (wave-local)

    if (compute) {
      // O += P V
      __builtin_amdgcn_s_setprio(1);
#pragma unroll
      for (int s2 = 0; s2 < 2; ++s2) {
        const bf16x8 pa = *(const bf16x8*)&p_lds[wv][c * 64 + ((s2 * 32 + g * 8) ^ ((c & 7) << 3))];
#pragma unroll
        for (int df = 0; df < 8; ++df) {
          const int row = df * 16 + c;
          const bf16x8 vb = *(const bf16x8*)&vt_lds[b][row * 64 + ((s2 * 32 + g * 8) ^ ((row & 7) << 3))];
          oacc[df] = __builtin_amdgcn_mfma_f32_16x16x32_bf16(pa, vb, oacc[df], 0, 0, 0);
        }
      }
      __builtin_amdgcn_s_setprio(0);
    }
    __syncthreads();
    b = nb;
  }

  float invl[4];
#pragma unroll
  for (int r = 0; r < 4; ++r) invl[r] = 1.f / lrow[r];
#pragma unroll
  for (int df = 0; df < 8; ++df)
#pragma unroll
    for (int r = 0; r < 4; ++r) {
      const int row = qw + g * 4 + r;
      const int col = h * HD + df * 16 + c;
      O[(size_t)row * HID + col] = f2bf(oacc[df][r] * invl[r]);
    }
}

// ---------------- launch ----------------

extern "C" void kernel_launch(void* const* d_in, const int* in_sizes, int n_in,
                              void* d_out, int out_size, void* d_ws, size_t ws_size,
                              hipStream_t stream) {
  const float* hidden = (const float*)d_in[0];
  const float* wq = (const float*)d_in[1];
  const float* wk = (const float*)d_in[2];
  const float* wv = (const float*)d_in[3];
  const float* wo = (const float*)d_in[4];
  float* out = (float*)d_out;

  char* ws = (char*)d_ws;
  u16* Xb  = (u16*)ws;                 ws += (size_t)SEQ * HID * 2;
  u16* Wqt = (u16*)ws;                 ws += (size_t)HID * HID * 2;
  u16* Wkt = (u16*)ws;                 ws += (size_t)HID * HID * 2;
  u16* Wvt = (u16*)ws;                 ws += (size_t)HID * HID * 2;
  u16* Wot = (u16*)ws;                 ws += (size_t)HID * HID * 2;
  u16* Qb  = (u16*)ws;                 ws += (size_t)SEQ * HID * 2;
  u16* Kb  = (u16*)ws;                 ws += (size_t)SEQ * HID * 2;
  u16* Vb  = (u16*)ws;                 ws += (size_t)SEQ * HID * 2;
  u16* Ob  = (u16*)ws;                 ws += (size_t)SEQ * HID * 2;
  float* ctab = (float*)ws;            ws += (size_t)SEQ * 64 * 4;
  float* stab = (float*)ws;            ws += (size_t)SEQ * 64 * 4;

  cast_f32_bf16<<<(SEQ * HID / 4 + 255) / 256, 256, 0, stream>>>(hidden, Xb, SEQ * HID / 4);

  dim3 tg(64, 64);
  transpose_cast<<<tg, 256, 0, stream>>>(wq, Wqt);
  transpose_cast<<<tg, 256, 0, stream>>>(wk, Wkt);
  transpose_cast<<<tg, 256, 0, stream>>>(wv, Wvt);
  transpose_cast<<<tg, 256, 0, stream>>>(wo, Wot);

  rope_table<<<(SEQ * 64) / 256, 256, 0, stream>>>(ctab, stab);

  dim3 gq(HID / 128, SEQ / 128, 3);
  gemm_qkv_kernel<<<gq, 256, 0, stream>>>(Xb, Wqt, Wkt, Wvt, Qb, Kb, Vb);

  rope_apply<<<(SEQ * NH * 64) / 256, 256, 0, stream>>>(Qb, Kb, ctab, stab);

  dim3 ga(SEQ / 128, NH);
  attn_kernel<<<ga, 512, 0, stream>>>(Qb, Kb, Vb, Ob);

  dim3 go(HID / 128, SEQ / 128);
  gemm_out_kernel<<<go, 256, 0, stream>>>(Ob, Wot, out);
}

// Round 4
// 291.354 us; speedup vs baseline: 1.1789x; 1.1789x over previous
//
#include <hip/hip_runtime.h>
#include <cstdint>
#include <cstddef>

typedef unsigned short u16;
typedef __bf16 bf16x8 __attribute__((ext_vector_type(8)));
typedef float f32x4 __attribute__((ext_vector_type(4)));
typedef unsigned short u16x8 __attribute__((ext_vector_type(8)));

#define SEQ 4096
#define HID 2048
#define NH 16
#define HD 128
#define WIN 1024

__device__ __forceinline__ float bf2f(u16 u) {
  union { unsigned int i; float f; } v; v.i = ((unsigned int)u) << 16; return v.f;
}
__device__ __forceinline__ u16 f2bf(float f) {
  union { float f; unsigned int i; } v; v.f = f;
  unsigned int r = v.i + 0x7FFFu + ((v.i >> 16) & 1u);
  return (u16)(r >> 16);
}
__device__ __forceinline__ u16 f2bf_rne(float f) {
  union { __bf16 b; u16 u; } v; v.b = (__bf16)f; return v.u;
}
__device__ __forceinline__ float exp2a(float x) {
  float r; asm("v_exp_f32 %0, %1" : "=v"(r) : "v"(x)); return r;
}
// XOR swizzle within a tile whose rows are (1<<L2R) bytes. Involution; keeps 16B alignment.
template<int L2R>
__device__ __forceinline__ unsigned swz(unsigned o) { return o ^ (((o >> L2R) & 7u) << 4); }

__device__ __forceinline__ void gload_lds16(const u16* g, u16* l) {
  __builtin_amdgcn_global_load_lds((const __attribute__((address_space(1))) void*)g,
                                   (__attribute__((address_space(3))) void*)l, 16, 0, 0);
}

// ---------------- elementwise prep ----------------

__global__ void cast_f32_bf16(const float* __restrict__ in, u16* __restrict__ out, int n4) {
  int i = blockIdx.x * blockDim.x + threadIdx.x;
  if (i < n4) {
    float4 v = ((const float4*)in)[i];
    union { u16 u[4]; unsigned long long ll; } r;
    r.u[0] = f2bf(v.x); r.u[1] = f2bf(v.y); r.u[2] = f2bf(v.z); r.u[3] = f2bf(v.w);
    ((unsigned long long*)out)[i] = r.ll;
  }
}

// 4 weight matrices (HID x HID, f32, row-major) -> bf16 transposed, one launch
__global__ void transpose_cast4(const float* __restrict__ w0, const float* __restrict__ w1,
                                const float* __restrict__ w2, const float* __restrict__ w3,
                                u16* __restrict__ o0, u16* __restrict__ o1,
                                u16* __restrict__ o2, u16* __restrict__ o3) {
  __shared__ float t[32][33];
  const float* W = (blockIdx.z == 0) ? w0 : (blockIdx.z == 1) ? w1 : (blockIdx.z == 2) ? w2 : w3;
  u16* Wt = (blockIdx.z == 0) ? o0 : (blockIdx.z == 1) ? o1 : (blockIdx.z == 2) ? o2 : o3;
  const int tx = threadIdx.x & 31, ty = threadIdx.x >> 5;  // ty 0..7
  const int x0 = blockIdx.x * 32, y0 = blockIdx.y * 32;
#pragma unroll
  for (int i = 0; i < 4; ++i)
    t[ty + i * 8][tx] = W[(size_t)(y0 + ty + i * 8) * HID + x0 + tx];
  __syncthreads();
#pragma unroll
  for (int i = 0; i < 4; ++i)
    Wt[(size_t)(x0 + ty + i * 8) * HID + y0 + tx] = f2bf(t[tx][ty + i * 8]);
}

__global__ void rope_table(float* __restrict__ ctab, float* __restrict__ stab) {
  int idx = blockIdx.x * blockDim.x + threadIdx.x;  // SEQ*64
  int pos = idx >> 6, i = idx & 63;
  float invf = expf(-(float)i * 0.14391156831212787f);  // ln(10000)/64
  float ang = (float)pos * invf;
  float s, c;
  sincosf(ang, &s, &c);
  ctab[idx] = c; stab[idx] = s;
}

// in-place RoPE on Q and K (bf16 [SEQ][HID])
__global__ void rope_apply(u16* __restrict__ Qb, u16* __restrict__ Kb,
                           const float* __restrict__ ctab, const float* __restrict__ stab) {
  int idx = blockIdx.x * blockDim.x + threadIdx.x;  // SEQ*NH*64
  int pos = idx >> 10;
  int rem = idx & 1023;
  int h = rem >> 6, i = rem & 63;
  size_t base = (size_t)pos * HID + h * HD + i;
  float c = ctab[(pos << 6) + i], s = stab[(pos << 6) + i];
  float q1 = bf2f(Qb[base]), q2 = bf2f(Qb[base + 64]);
  Qb[base] = f2bf(q1 * c - q2 * s);
  Qb[base + 64] = f2bf(q2 * c + q1 * s);
  float k1 = bf2f(Kb[base]), k2 = bf2f(Kb[base + 64]);
  Kb[base] = f2bf(k1 * c - k2 * s);
  Kb[base + 64] = f2bf(k2 * c + k1 * s);
}

// ---------------- GEMM: C[M,N] = A[M,K] * Bt[N,K]^T, bf16 in, fp32 acc ----------------
// 128x128 tile, BK=64, 4 waves (2x2), double-buffered LDS, global_load_lds staging with
// source-side swizzle (linear LDS dest) + swizzled ds_read (rule #21).

template<bool OUT_F32>
__device__ __forceinline__ void gemm_body(const u16* __restrict__ A, const u16* __restrict__ Bt,
                                          void* __restrict__ C, int brow, int bcol,
                                          u16 (&ldsA)[2][8192], u16 (&ldsB)[2][8192]) {
  const int lane = threadIdx.x & 63;
  const int wv = threadIdx.x >> 6;
  const int wr = wv >> 1, wc = wv & 1;
  const int K = HID, N = HID;

  const f32x4 zero = {0.f, 0.f, 0.f, 0.f};
  f32x4 acc[4][4];
#pragma unroll
  for (int m = 0; m < 4; ++m)
#pragma unroll
    for (int n = 0; n < 4; ++n) acc[m][n] = zero;

  auto stage = [&](int buf, int kt) {
    const int k0 = kt * 64;
#pragma unroll
    for (int i = 0; i < 4; ++i) {
      unsigned o = ((unsigned)(wv * 4 + i) * 64 + (unsigned)lane) * 16u;
      unsigned r = o >> 7;                 // tile row (128B rows: 64 bf16)
      unsigned cb = swz<7>(o) & 127u;      // swizzled col-bytes within row
      const size_t gcol = (size_t)k0 + (cb >> 1);
      gload_lds16(A + (size_t)(brow + r) * K + gcol, &ldsA[buf][(wv * 4 + i) * 512]);
      gload_lds16(Bt + (size_t)(bcol + r) * K + gcol, &ldsB[buf][(wv * 4 + i) * 512]);
    }
  };

  stage(0, 0);
  __syncthreads();
  int buf = 0;
  const int nt = K / 64;
  for (int kt = 0; kt < nt; ++kt) {
    if (kt + 1 < nt) stage(buf ^ 1, kt + 1);
    __builtin_amdgcn_s_setprio(1);
#pragma unroll
    for (int s = 0; s < 2; ++s) {
      const unsigned kb = (unsigned)(s * 64 + ((lane >> 4) & 3) * 16);
      bf16x8 af[4], bfv[4];
#pragma unroll
      for (int m = 0; m < 4; ++m) {
        unsigned row = wr * 64 + m * 16 + (lane & 15);
        af[m] = *(const bf16x8*)((const char*)&ldsA[buf][0] + swz<7>(row * 128 + kb));
      }
#pragma unroll
      for (int n = 0; n < 4; ++n) {
        unsigned row = wc * 64 + n * 16 + (lane & 15);
        bfv[n] = *(const bf16x8*)((const char*)&ldsB[buf][0] + swz<7>(row * 128 + kb));
      }
#pragma unroll
      for (int m = 0; m < 4; ++m)
#pragma unroll
        for (int n = 0; n < 4; ++n)
          acc[m][n] = __builtin_amdgcn_mfma_f32_16x16x32_bf16(af[m], bfv[n], acc[m][n], 0, 0, 0);
    }
    __builtin_amdgcn_s_setprio(0);
    __syncthreads();
    buf ^= 1;
  }

#pragma unroll
  for (int m = 0; m < 4; ++m) {
    const int rbase = brow + wr * 64 + m * 16 + ((lane >> 4) & 3) * 4;
#pragma unroll
    for (int n = 0; n < 4; ++n) {
      const int cbase = bcol + wc * 64 + n * 16 + (lane & 15);
#pragma unroll
      for (int r = 0; r < 4; ++r) {
        const size_t idx = (size_t)(rbase + r) * N + cbase;
        if (OUT_F32) ((float*)C)[idx] = acc[m][n][r];
        else ((u16*)C)[idx] = f2bf(acc[m][n][r]);
      }
    }
  }
}

__global__ __launch_bounds__(256, 2) void gemm_qkv_kernel(
    const u16* __restrict__ X, const u16* __restrict__ Wqt, const u16* __restrict__ Wkt,
    const u16* __restrict__ Wvt, u16* __restrict__ Qo, u16* __restrict__ Ko, u16* __restrict__ Vo) {
  __shared__ u16 ldsA[2][8192];
  __shared__ u16 ldsB[2][8192];
  // T1 bijective XCD swizzle: 1536 blocks = 8 * 192
  int flat = (blockIdx.z * 32 + blockIdx.y) * 16 + blockIdx.x;
  int nf = (flat & 7) * 192 + (flat >> 3);
  int bx = nf & 15, by = (nf >> 4) & 31, bz = nf >> 9;
  const u16* Bt = (bz == 0) ? Wqt : (bz == 1) ? Wkt : Wvt;
  u16* C = (bz == 0) ? Qo : (bz == 1) ? Ko : Vo;
  gemm_body<false>(X, Bt, C, by * 128, bx * 128, ldsA, ldsB);
}

__global__ __launch_bounds__(256, 2) void gemm_out_kernel(
    const u16* __restrict__ Ob, const u16* __restrict__ Wot, float* __restrict__ out) {
  __shared__ u16 ldsA[2][8192];
  __shared__ u16 ldsB[2][8192];
  // 512 blocks = 8 * 64
  int flat = blockIdx.y * 16 + blockIdx.x;
  int nf = (flat & 7) * 64 + (flat >> 3);
  int bx = nf & 15, by = nf >> 4;
  gemm_body<true>(Ob, Wot, out, by * 128, bx * 128, ldsA, ldsB);
}

// ---------------- windowed flash attention ----------------
// block = (head, 64 q-rows); 4 waves x 16 rows; KV tiles of 64.  (R2 geometry: 1024 blocks,
// half resident per XCD at a time -> one head's K/V hot in L2.)
// Schedule: double-buffered K (global_load_lds) + V (reg-staged, async split),
// one barrier per tile; mask only on diagonal/window-edge tiles; defer-rescale.
// LDS layouts XOR-swizzled no-pad (conflict-free on write and read sides): 72KB -> 2 blocks/CU.

__global__ __launch_bounds__(256, 2) void attn_kernel(
    const u16* __restrict__ Q, const u16* __restrict__ K,
    const u16* __restrict__ V, u16* __restrict__ O) {
  __shared__ u16 k_lds[2][8192];   // [64 keys][128 d] swizzled (256B rows), dbuf   32KB
  __shared__ u16 vt_lds[2][8192];  // V^T [128 d][64 keys] swizzled (128B rows), dbuf 32KB
  __shared__ u16 p_lds[4][1024];   // per-wave P [16 q][64 k] swizzled               8KB

  const int lane = threadIdx.x & 63;
  const int wv = threadIdx.x >> 6;
  const int g = lane >> 4;   // 0..3
  const int c = lane & 15;

  // T1: chunked swizzle so one XCD sees contiguous q-blocks of the same head
  int flat = blockIdx.y * 64 + blockIdx.x;       // 1024 = 8 * 128
  int nf = (flat & 7) * 128 + (flat >> 3);
  const int q0 = (nf & 63) * 64;
  const int h = nf >> 6;

  // ---- stage Q via k_lds[0], load fragments ----
#pragma unroll
  for (int i = 0; i < 4; ++i) {
    unsigned o = ((unsigned)(wv * 4 + i) * 64 + (unsigned)lane) * 16u;
    unsigned r = o >> 8;
    unsigned cb = swz<8>(o) & 255u;
    gload_lds16(Q + (size_t)(q0 + r) * HID + h * HD + (cb >> 1), &k_lds[0][(wv * 4 + i) * 512]);
  }
  __syncthreads();
  bf16x8 qf[4];
#pragma unroll
  for (int s = 0; s < 4; ++s) {
    unsigned row = wv * 16 + c;
    qf[s] = *(const bf16x8*)((const char*)&k_lds[0][0] + swz<8>(row * 256 + s * 64 + g * 16));
  }
  __syncthreads();

  const int t_start = (q0 >= WIN) ? (q0 - WIN) : 0;

  // ---- prologue: stage K[t_start] + VT[t_start] into buffer 0 ----
#pragma unroll
  for (int i = 0; i < 4; ++i) {
    unsigned o = ((unsigned)(wv * 4 + i) * 64 + (unsigned)lane) * 16u;
    unsigned r = o >> 8;
    unsigned cb = swz<8>(o) & 255u;
    gload_lds16(K + (size_t)(t_start + r) * HID + h * HD + (cb >> 1), &k_lds[0][(wv * 4 + i) * 512]);
  }
  {
    const u16x8* src = (const u16x8*)(V + (size_t)(t_start + lane) * HID + h * HD + wv * 32);
#pragma unroll
    for (int it = 0; it < 4; ++it) {
      u16x8 vv = src[it];
#pragma unroll
      for (int j = 0; j < 8; ++j) {
        const int d = wv * 32 + it * 8 + j;
        vt_lds[0][d * 64 + (lane ^ ((d & 7) << 3))] = vv[j];
      }
    }
  }
  __syncthreads();

  const f32x4 zero = {0.f, 0.f, 0.f, 0.f};
  float mrow[4], lrow[4];
  f32x4 oacc[8];
#pragma unroll
  for (int r = 0; r < 4; ++r) { mrow[r] = -1e30f; lrow[r] = 0.f; }
#pragma unroll
  for (int d = 0; d < 8; ++d) oacc[d] = zero;

  const float scale2 = 0.12751743f;  // (1/sqrt(128)) * log2(e)
  int b = 0;

  for (int t0 = t_start; t0 <= q0; t0 += 64) {
    const int nb = b ^ 1;
    const bool has_next = (t0 + 64 <= q0);

    // issue next tile's staging early (T14 async split)
    u16x8 vr[4];
    if (has_next) {
#pragma unroll
      for (int i = 0; i < 4; ++i) {
        unsigned o = ((unsigned)(wv * 4 + i) * 64 + (unsigned)lane) * 16u;
        unsigned r = o >> 8;
        unsigned cb = swz<8>(o) & 255u;
        gload_lds16(K + (size_t)(t0 + 64 + r) * HID + h * HD + (cb >> 1),
                    &k_lds[nb][(wv * 4 + i) * 512]);
      }
      const u16x8* src = (const u16x8*)(V + (size_t)(t0 + 64 + lane) * HID + h * HD + wv * 32);
#pragma unroll
      for (int it = 0; it < 4; ++it) vr[it] = src[it];
    }

    // S = Q K^T  (16 q x 64 keys per wave)
    f32x4 sa[4];
#pragma unroll
    for (int kf = 0; kf < 4; ++kf) sa[kf] = zero;
    __builtin_amdgcn_s_setprio(1);
#pragma unroll
    for (int s = 0; s < 4; ++s) {
#pragma unroll
      for (int kf = 0; kf < 4; ++kf) {
        unsigned row = kf * 16 + c;
        bf16x8 kb = *(const bf16x8*)((const char*)&k_lds[b][0] + swz<8>(row * 256 + s * 64 + g * 16));
        sa[kf] = __builtin_amdgcn_mfma_f32_16x16x32_bf16(qf[s], kb, sa[kf], 0, 0, 0);
      }
    }
    __builtin_amdgcn_s_setprio(0);

    // scale (exp2 domain) + mask only where needed
    const int qbase = q0 + wv * 16 + g * 4;
    const bool diag = (t0 == q0);
    const bool lowm = (q0 >= WIN) && (t0 == t_start);
    if (diag) {
#pragma unroll
      for (int kf = 0; kf < 4; ++kf) {
        const int kpos = t0 + kf * 16 + c;
#pragma unroll
        for (int r = 0; r < 4; ++r) {
          float x = sa[kf][r] * scale2;
          sa[kf][r] = (kpos <= qbase + r) ? x : -1e30f;
        }
      }
    } else if (lowm) {
#pragma unroll
      for (int kf = 0; kf < 4; ++kf) {
        const int kpos = t0 + kf * 16 + c;
#pragma unroll
        for (int r = 0; r < 4; ++r) {
          float x = sa[kf][r] * scale2;
          sa[kf][r] = (kpos > qbase + r - WIN) ? x : -1e30f;
        }
      }
    } else {
#pragma unroll
      for (int kf = 0; kf < 4; ++kf)
#pragma unroll
        for (int r = 0; r < 4; ++r) sa[kf][r] *= scale2;
    }

    // row max (in-reg over kf, then 16-lane shuffle)
    float tmax[4];
#pragma unroll
    for (int r = 0; r < 4; ++r)
      tmax[r] = fmaxf(fmaxf(sa[0][r], sa[1][r]), fmaxf(sa[2][r], sa[3][r]));
#pragma unroll
    for (int r = 0; r < 4; ++r)
#pragma unroll
      for (int d = 1; d < 16; d <<= 1)
        tmax[r] = fmaxf(tmax[r], __shfl_xor(tmax[r], d, 16));

    // T13 defer-rescale: skip whole-wave when no row grew past mrow+8
    bool okl = (tmax[0] <= mrow[0] + 8.f) && (tmax[1] <= mrow[1] + 8.f) &&
               (tmax[2] <= mrow[2] + 8.f) && (tmax[3] <= mrow[3] + 8.f);
    if (!__all((int)okl)) {
#pragma unroll
      for (int r = 0; r < 4; ++r) {
        const float mn = fmaxf(mrow[r], tmax[r]);
        const float al = exp2a(mrow[r] - mn);
        mrow[r] = mn;
        lrow[r] *= al;
#pragma unroll
        for (int df = 0; df < 8; ++df) oacc[df][r] *= al;
      }
    }

    // P = exp2(S - m); row-sum
    float rs[4] = {0.f, 0.f, 0.f, 0.f};
    if (diag || lowm) {
#pragma unroll
      for (int kf = 0; kf < 4; ++kf)
#pragma unroll
        for (int r = 0; r < 4; ++r) {
          const float x = sa[kf][r];
          const float p = (x < -1e29f) ? 0.f : exp2a(x - mrow[r]);
          sa[kf][r] = p; rs[r] += p;
        }
    } else {
#pragma unroll
      for (int kf = 0; kf < 4; ++kf)
#pragma unroll
        for (int r = 0; r < 4; ++r) {
          const float p = exp2a(sa[kf][r] - mrow[r]);
          sa[kf][r] = p; rs[r] += p;
        }
    }
#pragma unroll
    for (int r = 0; r < 4; ++r) {
#pragma unroll
      for (int d = 1; d < 16; d <<= 1) rs[r] += __shfl_xor(rs[r], d, 16);
      lrow[r] += rs[r];
    }

    // P -> per-wave LDS (swizzled [16][64])
#pragma unroll
    for (int kf = 0; kf < 4; ++kf)
#pragma unroll
      for (int r = 0; r < 4; ++r) {
        const int q = g * 4 + r;
        p_lds[wv][q * 64 + ((kf * 16 + c) ^ ((q & 7) << 3))] = f2bf_rne(sa[kf][r]);
      }

    // write next tile's V^T (loads have had QK^T + softmax to land)
    if (has_next) {
#pragma unroll
      for (int it = 0; it < 4; ++it)
#pragma unroll
        for (int j = 0; j < 8; ++j) {
          const int d = wv * 32 + it * 8 + j;
          vt_lds[nb][d * 64 + (lane ^ ((d & 7) << 3))] = vr[it][j];
        }
    }

    asm volatile("" ::: "memory");  // order p_lds writes before PV reads (wave-local)

    // O += P V
    __builtin_amdgcn_s_setprio(1);
#pragma unroll
    for (int s2 = 0; s2 < 2; ++s2) {
      const bf16x8 pa = *(const bf16x8*)&p_lds[wv][c * 64 + ((s2 * 32 + g * 8) ^ ((c & 7) << 3))];
#pragma unroll
      for (int df = 0; df < 8; ++df) {
        const int row = df * 16 + c;
        const bf16x8 vb = *(const bf16x8*)&vt_lds[b][row * 64 + ((s2 * 32 + g * 8) ^ ((row & 7) << 3))];
        oacc[df] = __builtin_amdgcn_mfma_f32_16x16x32_bf16(pa, vb, oacc[df], 0, 0, 0);
      }
    }
    __builtin_amdgcn_s_setprio(0);
    __syncthreads();
    b = nb;
  }

  float invl[4];
#pragma unroll
  for (int r = 0; r < 4; ++r) invl[r] = 1.f / lrow[r];
#pragma unroll
  for (int df = 0; df < 8; ++df)
#pragma unroll
    for (int r = 0; r < 4; ++r) {
      const int row = q0 + wv * 16 + g * 4 + r;
      const int col = h * HD + df * 16 + c;
      O[(size_t)row * HID + col] = f2bf(oacc[df][r] * invl[r]);
    }
}

// ---------------- launch ----------------

extern "C" void kernel_launch(void* const* d_in, const int* in_sizes, int n_in,
                              void* d_out, int out_size, void* d_ws, size_t ws_size,
                              hipStream_t stream) {
  const float* hidden = (const float*)d_in[0];
  const float* wq = (const float*)d_in[1];
  const float* wk = (const float*)d_in[2];
  const float* wv = (const float*)d_in[3];
  const float* wo = (const float*)d_in[4];
  float* out = (float*)d_out;

  char* ws = (char*)d_ws;
  u16* Xb  = (u16*)ws;                 ws += (size_t)SEQ * HID * 2;
  u16* Wqt = (u16*)ws;                 ws += (size_t)HID * HID * 2;
  u16* Wkt = (u16*)ws;                 ws += (size_t)HID * HID * 2;
  u16* Wvt = (u16*)ws;                 ws += (size_t)HID * HID * 2;
  u16* Wot = (u16*)ws;                 ws += (size_t)HID * HID * 2;
  u16* Qb  = (u16*)ws;                 ws += (size_t)SEQ * HID * 2;
  u16* Kb  = (u16*)ws;                 ws += (size_t)SEQ * HID * 2;
  u16* Vb  = (u16*)ws;                 ws += (size_t)SEQ * HID * 2;
  u16* Ob  = (u16*)ws;                 ws += (size_t)SEQ * HID * 2;
  float* ctab = (float*)ws;            ws += (size_t)SEQ * 64 * 4;
  float* stab = (float*)ws;            ws += (size_t)SEQ * 64 * 4;

  cast_f32_bf16<<<(SEQ * HID / 4 + 255) / 256, 256, 0, stream>>>(hidden, Xb, SEQ * HID / 4);

  dim3 tg(64, 64, 4);
  transpose_cast4<<<tg, 256, 0, stream>>>(wq, wk, wv, wo, Wqt, Wkt, Wvt, Wot);

  rope_table<<<(SEQ * 64) / 256, 256, 0, stream>>>(ctab, stab);

  dim3 gq(HID / 128, SEQ / 128, 3);
  gemm_qkv_kernel<<<gq, 256, 0, stream>>>(Xb, Wqt, Wkt, Wvt, Qb, Kb, Vb);

  rope_apply<<<(SEQ * NH * 64) / 256, 256, 0, stream>>>(Qb, Kb, ctab, stab);

  dim3 ga(SEQ / 64, NH);
  attn_kernel<<<ga, 256, 0, stream>>>(Qb, Kb, Vb, Ob);

  dim3 go(HID / 128, SEQ / 128);
  gemm_out_kernel<<<go, 256, 0, stream>>>(Ob, Wot, out);
}